// Round 5
// baseline (658.521 us; speedup 1.0000x reference)
//
#include <hip/hip_runtime.h>
#include <hip/hip_bf16.h>
#include <stdint.h>
#include <stddef.h>

typedef __bf16 bf16;
typedef __bf16 bf16x8 __attribute__((ext_vector_type(8)));
typedef __bf16 bf16x4 __attribute__((ext_vector_type(4)));
typedef float f32x4 __attribute__((ext_vector_type(4)));

#define HID 1024
#define IDIM 2048
#define NE 8
#define NTOK 4096
#define NSLOT 12800
#define SH_BASE 8704
#define MAX_TILES 200
#define LDA 72   // LDS row stride for 64-wide tiles: 144B = 4-bank rotation/row -> 2-way max (free)

// ---- workspace byte offsets ----
#define WS_META    0
#define WS_PERM    4096              // u32[12800]
#define WS_TOKE    55296             // i32[8192]
#define WS_TOKW    88064             // f32[8192]
#define WS_SLOTOF  120832            // u32[8192]
#define WS_GATET   153600            // bf16[8][2048][1024]
#define WS_UPT     33708032
#define WS_DOWNT   67262464          // bf16[8][1024][2048]
#define WS_SGT     100816896         // bf16[2048][1024]
#define WS_SUT     105011200
#define WS_SDT     109205504         // bf16[1024][2048]
#define WS_ACT     113399808         // bf16[12800][2048]
#define WS_DOUT    165828608         // bf16[12800][1024]

// meta u32-index layout
#define M_CNT 0
#define M_CUR 8
#define M_PSUM 16
#define M_ZSUM 24
#define M_AOFF 32
#define M_NTILE 48
#define M_TE 64
#define M_TB 320

#define OUT_AUX 4194304
#define OUT_Z   4194305
#define OUT_LG  4194306

__device__ __forceinline__ int imin(int a, int b) { return a < b ? a : b; }

__global__ void zero_kernel(uint32_t* meta) {
    if (threadIdx.x < 32) meta[threadIdx.x] = 0;
}

// 16 tokens per 1024-thread block; block-level LDS aggregation of atomics
__global__ __launch_bounds__(1024) void router_kernel(
    const float* __restrict__ x, const float* __restrict__ rw,
    float* __restrict__ out, uint32_t* meta, int* tok_e, float* tok_w)
{
    __shared__ float s_psum[NE];
    __shared__ float s_zsum;
    __shared__ uint32_t s_cnt[NE];
    int tid = threadIdx.x;
    if (tid < NE) { s_psum[tid] = 0.f; s_cnt[tid] = 0u; }
    if (tid == NE) s_zsum = 0.f;
    __syncthreads();

    int lane = tid & 63, wv = tid >> 6;
    int t = blockIdx.x * 16 + wv;
    float acc[NE];
#pragma unroll
    for (int e = 0; e < NE; e++) acc[e] = 0.f;
#pragma unroll
    for (int it = 0; it < 4; it++) {
        int h0 = (lane + it * 64) * 4;
        f32x4 xv = *(const f32x4*)&x[(size_t)t * HID + h0];
#pragma unroll
        for (int j = 0; j < 4; j++) {
            float xf = xv[j];
            const float* wrow = rw + (size_t)(h0 + j) * NE;
            f32x4 w0 = *(const f32x4*)wrow;
            f32x4 w1 = *(const f32x4*)(wrow + 4);
#pragma unroll
            for (int e = 0; e < 4; e++) { acc[e] += xf * w0[e]; acc[e + 4] += xf * w1[e]; }
        }
    }
#pragma unroll
    for (int off = 32; off >= 1; off >>= 1)
#pragma unroll
        for (int e = 0; e < NE; e++) acc[e] += __shfl_xor(acc[e], off);

    if (lane == 0) {
        float mx = acc[0];
        for (int e = 1; e < NE; e++) mx = fmaxf(mx, acc[e]);
        float p[NE], s = 0.f;
        for (int e = 0; e < NE; e++) { p[e] = __expf(acc[e] - mx); s += p[e]; }
        float lse = mx + __logf(s);
        atomicAdd(&s_zsum, lse * lse);
        float inv = 1.f / s;
        for (int e = 0; e < NE; e++) {
            p[e] *= inv;
            atomicAdd(&s_psum[e], p[e]);
            out[(size_t)OUT_LG + (size_t)t * NE + e] = acc[e];
        }
        int e0 = 0;
        for (int e = 1; e < NE; e++) if (p[e] > p[e0]) e0 = e;
        int e1 = (e0 == 0) ? 1 : 0;
        for (int e = 0; e < NE; e++) if (e != e0 && p[e] > p[e1]) e1 = e;
        float wn = 1.f / (p[e0] + p[e1]);
        tok_e[2 * t] = e0; tok_e[2 * t + 1] = e1;
        tok_w[2 * t] = p[e0] * wn; tok_w[2 * t + 1] = p[e1] * wn;
        atomicAdd(&s_cnt[e0], 1u);
        atomicAdd(&s_cnt[e1], 1u);
    }
    __syncthreads();
    if (tid < NE) {
        atomicAdd((float*)&meta[M_PSUM + tid], s_psum[tid]);
        atomicAdd(&meta[M_CNT + tid], s_cnt[tid]);
    }
    if (tid == NE) atomicAdd((float*)&meta[M_ZSUM], s_zsum);
}

__global__ void offsets_kernel(uint32_t* meta, float* out) {
    if (threadIdx.x != 0 || blockIdx.x != 0) return;
    uint32_t off = 0, idx = 0;
    for (int e = 0; e < NE; e++) {
        meta[M_AOFF + e] = off;
        uint32_t c = meta[M_CNT + e];
        uint32_t nt = (c + 63) >> 6;
        for (uint32_t j = 0; j < nt && idx < MAX_TILES; j++) {
            meta[M_TE + idx] = e;
            meta[M_TB + idx] = off + j * 64;
            idx++;
        }
        off += nt * 64;
    }
    meta[M_AOFF + NE] = off;
    for (uint32_t j = 0; j < NTOK / 64 && idx < MAX_TILES; j++) {
        meta[M_TE + idx] = NE;
        meta[M_TB + idx] = SH_BASE + j * 64;
        idx++;
    }
    meta[M_NTILE] = idx;
    float aux = 0.f;
    for (int e = 0; e < NE; e++) {
        float tpe = (float)meta[M_CNT + e] / (2.f * NTOK);
        float ppe = ((float*)meta)[M_PSUM + e] / (float)NTOK;
        aux += tpe * ppe;
    }
    out[OUT_AUX] = aux * NE;
    out[OUT_Z] = ((float*)meta)[M_ZSUM] / (float)NTOK;
}

__global__ void fill_kernel(uint32_t* perm) {
    int g = blockIdx.x * 256 + threadIdx.x;
    if (g < NSLOT) perm[g] = (g < SH_BASE) ? 0u : (uint32_t)(g - SH_BASE);
}

// wave-aggregated slot assignment: one atomic per (wave, expert)
__global__ void dispatch_kernel(uint32_t* meta, const int* tok_e,
                                uint32_t* perm, uint32_t* slot_of) {
    int t = blockIdx.x * 256 + threadIdx.x;
    int lane = threadIdx.x & 63;
    for (int k = 0; k < 2; k++) {
        int e = tok_e[2 * t + k] & 7;
#pragma unroll
        for (int ee = 0; ee < NE; ee++) {
            bool mine = (e == ee);
            unsigned long long mask = __ballot(mine);
            if (mask == 0ull) continue;
            int leader = __ffsll((unsigned long long)mask) - 1;
            uint32_t wbase = 0;
            if (lane == leader)
                wbase = atomicAdd(&meta[M_CUR + ee], (uint32_t)__popcll(mask));
            wbase = __shfl(wbase, leader);
            if (mine) {
                uint32_t myrank = (uint32_t)__popcll(mask & ((1ull << lane) - 1ull));
                uint32_t slot = meta[M_AOFF + ee] + wbase + myrank;
                if (slot >= NSLOT) slot = 0;
                perm[slot] = (uint32_t)t;
                slot_of[2 * t + k] = slot;
            }
        }
    }
}

// transpose + f32->bf16 convert, 27 matrices of 2M elems: dst[c][r] = (bf16)src[r][c]
__global__ __launch_bounds__(256) void transpose_kernel(
    const float* gw, const float* uw, const float* dw,
    const float* sg, const float* su, const float* sd, char* ws)
{
    int mat = blockIdx.x >> 9, tile = blockIdx.x & 511;
    const float* src; bf16* dst; int R, C;
    const size_t MSZ = (size_t)HID * IDIM;
    if (mat < 8)       { src = gw + mat * MSZ;        dst = (bf16*)(ws + WS_GATET) + mat * MSZ; R = HID;  C = IDIM; }
    else if (mat < 16) { src = uw + (mat - 8) * MSZ;  dst = (bf16*)(ws + WS_UPT) + (mat - 8) * MSZ; R = HID; C = IDIM; }
    else if (mat < 24) { src = dw + (mat - 16) * MSZ; dst = (bf16*)(ws + WS_DOWNT) + (mat - 16) * MSZ; R = IDIM; C = HID; }
    else if (mat == 24){ src = sg; dst = (bf16*)(ws + WS_SGT); R = HID; C = IDIM; }
    else if (mat == 25){ src = su; dst = (bf16*)(ws + WS_SUT); R = HID; C = IDIM; }
    else               { src = sd; dst = (bf16*)(ws + WS_SDT); R = IDIM; C = HID; }
    int tpr = C >> 6;
    int r0 = (tile / tpr) * 64, c0 = (tile % tpr) * 64;
    __shared__ bf16 tl[64][65];
    int tid = threadIdx.x;
#pragma unroll
    for (int it = 0; it < 4; it++) {
        int idx = tid + it * 256;                  // [0,1024)
        int r = idx >> 4, c4 = (idx & 15) * 4;
        f32x4 v = *(const f32x4*)&src[(size_t)(r0 + r) * C + c0 + c4];
#pragma unroll
        for (int j = 0; j < 4; j++) tl[c4 + j][r] = (bf16)v[j];
    }
    __syncthreads();
#pragma unroll
    for (int it = 0; it < 2; it++) {
        int idx = tid + it * 256;                  // [0,512)
        int rr = idx >> 3, c8 = (idx & 7) * 8;
        bf16x8 o;
#pragma unroll
        for (int j = 0; j < 8; j++) o[j] = tl[rr][c8 + j];
        *(bf16x8*)&dst[(size_t)(c0 + rr) * R + r0 + c8] = o;
    }
}

// stage 1: act[slot][i] = silu(x@gateT) * (x@upT), tile 64(M) x 128(N), BK=64
__global__ __launch_bounds__(256) void stage1_kernel(
    const float* __restrict__ x, char* __restrict__ ws)
{
    uint32_t* meta = (uint32_t*)(ws + WS_META);
    int mtile = blockIdx.y;
    int ntile = imin((int)meta[M_NTILE], MAX_TILES);
    if (mtile >= ntile) return;
    int e = imin((int)meta[M_TE + mtile], NE);
    int slot0 = imin((int)meta[M_TB + mtile], NSLOT - 64);
    if (slot0 < 0) slot0 = 0;
    int n0 = blockIdx.x * 128;
    const bf16* Bg = (e < NE) ? (const bf16*)(ws + WS_GATET) + (size_t)e * HID * IDIM
                              : (const bf16*)(ws + WS_SGT);
    const bf16* Bu = (e < NE) ? (const bf16*)(ws + WS_UPT) + (size_t)e * HID * IDIM
                              : (const bf16*)(ws + WS_SUT);
    const uint32_t* perm = (const uint32_t*)(ws + WS_PERM);
    bf16* act = (bf16*)(ws + WS_ACT);

    __shared__ bf16 As[64 * LDA];
    __shared__ bf16 Bgs[128 * LDA];
    __shared__ bf16 Bus[128 * LDA];
    __shared__ int toks[64];
    int tid = threadIdx.x;
    if (tid < 64) toks[tid] = (int)(perm[slot0 + tid] & (NTOK - 1));
    __syncthreads();

    int lane = tid & 63, wv = tid >> 6;
    int q = lane >> 4, m = lane & 15;
    f32x4 zero4 = {0.f, 0.f, 0.f, 0.f};
    f32x4 accg[4][2], accu[4][2];
#pragma unroll
    for (int a = 0; a < 4; a++)
#pragma unroll
        for (int b = 0; b < 2; b++) { accg[a][b] = zero4; accu[a][b] = zero4; }

    for (int k0 = 0; k0 < HID; k0 += 64) {
        // A: f32 global -> bf16 LDS (64 rows x 64 cols)
#pragma unroll
        for (int it = 0; it < 4; it++) {
            int idx = tid + it * 256;              // [0,1024)
            int r = idx >> 4, c4 = (idx & 15) * 4;
            f32x4 v = *(const f32x4*)&x[(size_t)toks[r] * HID + k0 + c4];
            bf16x4 b;
#pragma unroll
            for (int j = 0; j < 4; j++) b[j] = (bf16)v[j];
            *(bf16x4*)&As[r * LDA + c4] = b;
        }
        // B: bf16 ws -> LDS (128 rows x 64 cols, two matrices)
#pragma unroll
        for (int it = 0; it < 4; it++) {
            int idx = tid + it * 256;
            int r = idx >> 3, c = (idx & 7) * 8;
            *(bf16x8*)&Bgs[r * LDA + c] = *(const bf16x8*)&Bg[(size_t)(n0 + r) * HID + k0 + c];
            *(bf16x8*)&Bus[r * LDA + c] = *(const bf16x8*)&Bu[(size_t)(n0 + r) * HID + k0 + c];
        }
        __syncthreads();
#pragma unroll
        for (int kk = 0; kk < 64; kk += 32) {
            bf16x8 af[4];
#pragma unroll
            for (int m4 = 0; m4 < 4; m4++)
                af[m4] = *(bf16x8*)&As[(m4 * 16 + m) * LDA + kk + q * 8];
#pragma unroll
            for (int nt = 0; nt < 2; nt++) {
                int n = wv * 32 + nt * 16 + m;
                bf16x8 bg = *(bf16x8*)&Bgs[n * LDA + kk + q * 8];
                bf16x8 bu = *(bf16x8*)&Bus[n * LDA + kk + q * 8];
#pragma unroll
                for (int m4 = 0; m4 < 4; m4++) {
                    accg[m4][nt] = __builtin_amdgcn_mfma_f32_16x16x32_bf16(af[m4], bg, accg[m4][nt], 0, 0, 0);
                    accu[m4][nt] = __builtin_amdgcn_mfma_f32_16x16x32_bf16(af[m4], bu, accu[m4][nt], 0, 0, 0);
                }
            }
        }
        __syncthreads();
    }
#pragma unroll
    for (int m4 = 0; m4 < 4; m4++)
#pragma unroll
        for (int nt = 0; nt < 2; nt++)
#pragma unroll
            for (int r = 0; r < 4; r++) {
                float g = accg[m4][nt][r], u = accu[m4][nt][r];
                float v = g / (1.f + __expf(-g)) * u;
                int slot = slot0 + m4 * 16 + q * 4 + r;
                int col = n0 + wv * 32 + nt * 16 + m;
                act[(size_t)slot * IDIM + col] = (bf16)v;
            }
}

// stage 2: down_out[slot][h] = act @ downT, tile 64 x 128, BK=64, K=2048
__global__ __launch_bounds__(256) void stage2_kernel(char* __restrict__ ws)
{
    uint32_t* meta = (uint32_t*)(ws + WS_META);
    int mtile = blockIdx.y;
    int ntile = imin((int)meta[M_NTILE], MAX_TILES);
    if (mtile >= ntile) return;
    int e = imin((int)meta[M_TE + mtile], NE);
    int slot0 = imin((int)meta[M_TB + mtile], NSLOT - 64);
    if (slot0 < 0) slot0 = 0;
    int n0 = blockIdx.x * 128;
    const bf16* B = (e < NE) ? (const bf16*)(ws + WS_DOWNT) + (size_t)e * HID * IDIM
                             : (const bf16*)(ws + WS_SDT);
    const bf16* act = (const bf16*)(ws + WS_ACT);
    bf16* dout = (bf16*)(ws + WS_DOUT);

    __shared__ bf16 As[64 * LDA];
    __shared__ bf16 Bs[128 * LDA];
    int tid = threadIdx.x;
    int lane = tid & 63, wv = tid >> 6;
    int q = lane >> 4, m = lane & 15;
    f32x4 zero4 = {0.f, 0.f, 0.f, 0.f};
    f32x4 acc[4][2];
#pragma unroll
    for (int a = 0; a < 4; a++)
#pragma unroll
        for (int b = 0; b < 2; b++) acc[a][b] = zero4;

    for (int k0 = 0; k0 < IDIM; k0 += 64) {
#pragma unroll
        for (int it = 0; it < 2; it++) {
            int idx = tid + it * 256;
            int r = idx >> 3, c = (idx & 7) * 8;
            *(bf16x8*)&As[r * LDA + c] = *(const bf16x8*)&act[(size_t)(slot0 + r) * IDIM + k0 + c];
        }
#pragma unroll
        for (int it = 0; it < 4; it++) {
            int idx = tid + it * 256;
            int r = idx >> 3, c = (idx & 7) * 8;
            *(bf16x8*)&Bs[r * LDA + c] = *(const bf16x8*)&B[(size_t)(n0 + r) * IDIM + k0 + c];
        }
        __syncthreads();
#pragma unroll
        for (int kk = 0; kk < 64; kk += 32) {
            bf16x8 af[4];
#pragma unroll
            for (int m4 = 0; m4 < 4; m4++)
                af[m4] = *(bf16x8*)&As[(m4 * 16 + m) * LDA + kk + q * 8];
#pragma unroll
            for (int nt = 0; nt < 2; nt++) {
                int n = wv * 32 + nt * 16 + m;
                bf16x8 bfr = *(bf16x8*)&Bs[n * LDA + kk + q * 8];
#pragma unroll
                for (int m4 = 0; m4 < 4; m4++)
                    acc[m4][nt] = __builtin_amdgcn_mfma_f32_16x16x32_bf16(af[m4], bfr, acc[m4][nt], 0, 0, 0);
            }
        }
        __syncthreads();
    }
#pragma unroll
    for (int m4 = 0; m4 < 4; m4++)
#pragma unroll
        for (int nt = 0; nt < 2; nt++)
#pragma unroll
            for (int r = 0; r < 4; r++) {
                int slot = slot0 + m4 * 16 + q * 4 + r;
                int col = n0 + wv * 32 + nt * 16 + m;
                dout[(size_t)slot * HID + col] = (bf16)acc[m4][nt][r];
            }
}

__global__ __launch_bounds__(256) void combine_kernel(char* __restrict__ ws, float* __restrict__ out)
{
    int g = blockIdx.x * 256 + threadIdx.x;
    int t = g >> 7;
    int hc = (g & 127) * 8;
    const uint32_t* slot_of = (const uint32_t*)(ws + WS_SLOTOF);
    const float* tok_w = (const float*)(ws + WS_TOKW);
    const bf16* dout = (const bf16*)(ws + WS_DOUT);
    uint32_t s0 = slot_of[2 * t], s1 = slot_of[2 * t + 1];
    if (s0 >= NSLOT) s0 = 0;
    if (s1 >= NSLOT) s1 = 0;
    float w0 = tok_w[2 * t], w1 = tok_w[2 * t + 1];
    bf16x8 a = *(const bf16x8*)&dout[(size_t)s0 * HID + hc];
    bf16x8 b = *(const bf16x8*)&dout[(size_t)s1 * HID + hc];
    bf16x8 c = *(const bf16x8*)&dout[(size_t)(SH_BASE + t) * HID + hc];
    f32x4 o0, o1;
#pragma unroll
    for (int j = 0; j < 4; j++)
        o0[j] = w0 * (float)a[j] + w1 * (float)b[j] + (float)c[j];
#pragma unroll
    for (int j = 0; j < 4; j++)
        o1[j] = w0 * (float)a[j + 4] + w1 * (float)b[j + 4] + (float)c[j + 4];
    *(f32x4*)&out[(size_t)t * HID + hc] = o0;
    *(f32x4*)&out[(size_t)t * HID + hc + 4] = o1;
}

extern "C" void kernel_launch(void* const* d_in, const int* in_sizes, int n_in,
                              void* d_out, int out_size, void* d_ws, size_t ws_size,
                              hipStream_t stream) {
    const float* x  = (const float*)d_in[0];
    const float* rw = (const float*)d_in[1];
    const float* gw = (const float*)d_in[2];
    const float* uw = (const float*)d_in[3];
    const float* dw = (const float*)d_in[4];
    const float* sg = (const float*)d_in[5];
    const float* su = (const float*)d_in[6];
    const float* sd = (const float*)d_in[7];
    float* out = (float*)d_out;
    char* ws = (char*)d_ws;
    uint32_t* meta = (uint32_t*)(ws + WS_META);
    uint32_t* perm = (uint32_t*)(ws + WS_PERM);
    int* tok_e = (int*)(ws + WS_TOKE);
    float* tok_w = (float*)(ws + WS_TOKW);
    uint32_t* slot_of = (uint32_t*)(ws + WS_SLOTOF);

    hipLaunchKernelGGL(zero_kernel, dim3(1), dim3(64), 0, stream, meta);
    hipLaunchKernelGGL(router_kernel, dim3(NTOK / 16), dim3(1024), 0, stream,
                       x, rw, out, meta, tok_e, tok_w);
    hipLaunchKernelGGL(offsets_kernel, dim3(1), dim3(64), 0, stream, meta, out);
    hipLaunchKernelGGL(fill_kernel, dim3((NSLOT + 255) / 256), dim3(256), 0, stream, perm);
    hipLaunchKernelGGL(dispatch_kernel, dim3(NTOK / 256), dim3(256), 0, stream,
                       meta, tok_e, perm, slot_of);
    hipLaunchKernelGGL(transpose_kernel, dim3(27 * 512), dim3(256), 0, stream,
                       gw, uw, dw, sg, su, sd, ws);
    hipLaunchKernelGGL(stage1_kernel, dim3(IDIM / 128, MAX_TILES), dim3(256), 0, stream, x, ws);
    hipLaunchKernelGGL(stage2_kernel, dim3(HID / 128, MAX_TILES), dim3(256), 0, stream, ws);
    hipLaunchKernelGGL(combine_kernel, dim3(NTOK * HID / 8 / 256), dim3(256), 0, stream, ws, out);
}

// Round 6
// 550.436 us; speedup vs baseline: 1.1964x; 1.1964x over previous
//
#include <hip/hip_runtime.h>
#include <hip/hip_bf16.h>
#include <stdint.h>
#include <stddef.h>

typedef __bf16 bf16;
typedef __bf16 bf16x8 __attribute__((ext_vector_type(8)));
typedef __bf16 bf16x4 __attribute__((ext_vector_type(4)));
typedef float f32x4 __attribute__((ext_vector_type(4)));

#define HID 1024
#define IDIM 2048
#define NE 8
#define NTOK 4096
#define NSLOT 12800
#define SH_BASE 8704
#define MAX_TILES 200

// ---- workspace byte offsets ----
#define WS_META    0
#define WS_PERM    4096              // u32[12800]
#define WS_TOKE    55296             // i32[8192]
#define WS_TOKW    88064             // f32[8192]
#define WS_SLOTOF  120832            // u32[8192]
#define WS_GATET   153600            // F-order bf16[8][I/32][ ... ] (2M elems/expert)
#define WS_UPT     33708032
#define WS_DOWNT   67262464
#define WS_SGT     100816896
#define WS_SUT     105011200
#define WS_SDT     109205504
#define WS_ACT     113399808         // act in stage2-A fragment order, 200 tiles
#define WS_DOUT    165828608         // dout row-major; first 8.4MB aliased as xbf16 until stage2

// meta u32-index layout
#define M_CNT 0
#define M_CUR 8
#define M_PSUM 16
#define M_ZSUM 24
#define M_AOFF 32
#define M_NTILE 48
#define M_TE 64
#define M_TB 320

#define OUT_AUX 4194304
#define OUT_Z   4194305
#define OUT_LG  4194306

__device__ __forceinline__ int imin(int a, int b) { return a < b ? a : b; }

typedef const __attribute__((address_space(1))) uint32_t* as1_u32p;
typedef __attribute__((address_space(3))) uint32_t* as3_u32p;

// async global->LDS, 16B per lane; LDS dst = wave-uniform base + lane*16
__device__ __forceinline__ void gload16(const void* g, void* l) {
    __builtin_amdgcn_global_load_lds((as1_u32p)g, (as3_u32p)l, 16, 0, 0);
}

__global__ void zero_kernel(uint32_t* meta) {
    if (threadIdx.x < 32) meta[threadIdx.x] = 0;
}

// 16 tokens/block; LDS-aggregated atomics; also emits x as bf16 (xbf aliases WS_DOUT)
__global__ __launch_bounds__(1024) void router_kernel(
    const float* __restrict__ x, const float* __restrict__ rw,
    float* __restrict__ out, uint32_t* meta, int* tok_e, float* tok_w,
    bf16* __restrict__ xbf)
{
    __shared__ float s_psum[NE];
    __shared__ float s_zsum;
    __shared__ uint32_t s_cnt[NE];
    int tid = threadIdx.x;
    if (tid < NE) { s_psum[tid] = 0.f; s_cnt[tid] = 0u; }
    if (tid == NE) s_zsum = 0.f;
    __syncthreads();

    int lane = tid & 63, wv = tid >> 6;
    int t = blockIdx.x * 16 + wv;
    float acc[NE];
#pragma unroll
    for (int e = 0; e < NE; e++) acc[e] = 0.f;
#pragma unroll
    for (int it = 0; it < 4; it++) {
        int h0 = (lane + it * 64) * 4;
        f32x4 xv = *(const f32x4*)&x[(size_t)t * HID + h0];
        bf16x4 xb;
#pragma unroll
        for (int j = 0; j < 4; j++) xb[j] = (bf16)xv[j];
        *(bf16x4*)&xbf[(size_t)t * HID + h0] = xb;
#pragma unroll
        for (int j = 0; j < 4; j++) {
            float xf = xv[j];
            const float* wrow = rw + (size_t)(h0 + j) * NE;
            f32x4 w0 = *(const f32x4*)wrow;
            f32x4 w1 = *(const f32x4*)(wrow + 4);
#pragma unroll
            for (int e = 0; e < 4; e++) { acc[e] += xf * w0[e]; acc[e + 4] += xf * w1[e]; }
        }
    }
#pragma unroll
    for (int off = 32; off >= 1; off >>= 1)
#pragma unroll
        for (int e = 0; e < NE; e++) acc[e] += __shfl_xor(acc[e], off);

    if (lane == 0) {
        float mx = acc[0];
        for (int e = 1; e < NE; e++) mx = fmaxf(mx, acc[e]);
        float p[NE], s = 0.f;
        for (int e = 0; e < NE; e++) { p[e] = __expf(acc[e] - mx); s += p[e]; }
        float lse = mx + __logf(s);
        atomicAdd(&s_zsum, lse * lse);
        float inv = 1.f / s;
        for (int e = 0; e < NE; e++) {
            p[e] *= inv;
            atomicAdd(&s_psum[e], p[e]);
            out[(size_t)OUT_LG + (size_t)t * NE + e] = acc[e];
        }
        int e0 = 0;
        for (int e = 1; e < NE; e++) if (p[e] > p[e0]) e0 = e;
        int e1 = (e0 == 0) ? 1 : 0;
        for (int e = 0; e < NE; e++) if (e != e0 && p[e] > p[e1]) e1 = e;
        float wn = 1.f / (p[e0] + p[e1]);
        tok_e[2 * t] = e0; tok_e[2 * t + 1] = e1;
        tok_w[2 * t] = p[e0] * wn; tok_w[2 * t + 1] = p[e1] * wn;
        atomicAdd(&s_cnt[e0], 1u);
        atomicAdd(&s_cnt[e1], 1u);
    }
    __syncthreads();
    if (tid < NE) {
        atomicAdd((float*)&meta[M_PSUM + tid], s_psum[tid]);
        atomicAdd(&meta[M_CNT + tid], s_cnt[tid]);
    }
    if (tid == NE) atomicAdd((float*)&meta[M_ZSUM], s_zsum);
}

__global__ void offsets_kernel(uint32_t* meta, float* out) {
    if (threadIdx.x != 0 || blockIdx.x != 0) return;
    uint32_t off = 0, idx = 0;
    for (int e = 0; e < NE; e++) {
        meta[M_AOFF + e] = off;
        uint32_t c = meta[M_CNT + e];
        uint32_t nt = (c + 63) >> 6;
        for (uint32_t j = 0; j < nt && idx < MAX_TILES; j++) {
            meta[M_TE + idx] = e;
            meta[M_TB + idx] = off + j * 64;
            idx++;
        }
        off += nt * 64;
    }
    meta[M_AOFF + NE] = off;
    for (uint32_t j = 0; j < NTOK / 64 && idx < MAX_TILES; j++) {
        meta[M_TE + idx] = NE;
        meta[M_TB + idx] = SH_BASE + j * 64;
        idx++;
    }
    meta[M_NTILE] = idx;
    float aux = 0.f;
    for (int e = 0; e < NE; e++) {
        float tpe = (float)meta[M_CNT + e] / (2.f * NTOK);
        float ppe = ((float*)meta)[M_PSUM + e] / (float)NTOK;
        aux += tpe * ppe;
    }
    out[OUT_AUX] = aux * NE;
    out[OUT_Z] = ((float*)meta)[M_ZSUM] / (float)NTOK;
}

__global__ void fill_kernel(uint32_t* perm) {
    int g = blockIdx.x * 256 + threadIdx.x;
    if (g < NSLOT) perm[g] = (g < SH_BASE) ? 0u : (uint32_t)(g - SH_BASE);
}

__global__ void dispatch_kernel(uint32_t* meta, const int* tok_e,
                                uint32_t* perm, uint32_t* slot_of) {
    int t = blockIdx.x * 256 + threadIdx.x;
    int lane = threadIdx.x & 63;
    for (int k = 0; k < 2; k++) {
        int e = tok_e[2 * t + k] & 7;
#pragma unroll
        for (int ee = 0; ee < NE; ee++) {
            bool mine = (e == ee);
            unsigned long long mask = __ballot(mine);
            if (mask == 0ull) continue;
            int leader = __ffsll((unsigned long long)mask) - 1;
            uint32_t wbase = 0;
            if (lane == leader)
                wbase = atomicAdd(&meta[M_CUR + ee], (uint32_t)__popcll(mask));
            wbase = __shfl(wbase, leader);
            if (mine) {
                uint32_t myrank = (uint32_t)__popcll(mask & ((1ull << lane) - 1ull));
                uint32_t slot = meta[M_AOFF + ee] + wbase + myrank;
                if (slot >= NSLOT) slot = 0;
                perm[slot] = (uint32_t)t;
                slot_of[2 * t + k] = slot;
            }
        }
    }
}

// fragment-order offset for weight W^T[n][k]: cell(n/32, k/32) -> [nt][q*16+m][8]
__device__ __forceinline__ size_t f_off(int n, int k, int KB32) {
    return ((size_t)((n >> 5) * KB32 + (k >> 5)) * 2 + ((n >> 4) & 1)) * 512
         + (size_t)((((k >> 3) & 3) * 16 + (n & 15)) * 8);
}

// transpose + f32->bf16 + fragment-order pack, 27 matrices
__global__ __launch_bounds__(256) void transpose_kernel(
    const float* gw, const float* uw, const float* dw,
    const float* sg, const float* su, const float* sd, char* ws)
{
    int mat = blockIdx.x >> 9, tile = blockIdx.x & 511;
    const float* src; bf16* dst; int R, C;
    const size_t MSZ = (size_t)HID * IDIM;
    if (mat < 8)       { src = gw + mat * MSZ;        dst = (bf16*)(ws + WS_GATET) + mat * MSZ; R = HID;  C = IDIM; }
    else if (mat < 16) { src = uw + (mat - 8) * MSZ;  dst = (bf16*)(ws + WS_UPT) + (mat - 8) * MSZ; R = HID; C = IDIM; }
    else if (mat < 24) { src = dw + (mat - 16) * MSZ; dst = (bf16*)(ws + WS_DOWNT) + (mat - 16) * MSZ; R = IDIM; C = HID; }
    else if (mat == 24){ src = sg; dst = (bf16*)(ws + WS_SGT); R = HID; C = IDIM; }
    else if (mat == 25){ src = su; dst = (bf16*)(ws + WS_SUT); R = HID; C = IDIM; }
    else               { src = sd; dst = (bf16*)(ws + WS_SDT); R = IDIM; C = HID; }
    int KB32 = R >> 5;                         // k-dim cells
    int tpr = C >> 6;
    int r0 = (tile / tpr) * 64, c0 = (tile % tpr) * 64;   // r0 = k, c0 = n
    __shared__ bf16 tl[64][65];
    int tid = threadIdx.x;
#pragma unroll
    for (int it = 0; it < 4; it++) {
        int idx = tid + it * 256;
        int r = idx >> 4, c4 = (idx & 15) * 4;
        f32x4 v = *(const f32x4*)&src[(size_t)(r0 + r) * C + c0 + c4];
#pragma unroll
        for (int j = 0; j < 4; j++) tl[c4 + j][r] = (bf16)v[j];
    }
    __syncthreads();
#pragma unroll
    for (int it = 0; it < 2; it++) {
        int idx = tid + it * 256;
        int rr = idx >> 3, c8 = (idx & 7) * 8;
        int n = c0 + rr, k = r0 + c8;
        bf16x8 o;
#pragma unroll
        for (int j = 0; j < 8; j++) o[j] = tl[rr][c8 + j];
        *(bf16x8*)&dst[f_off(n, k, KB32)] = o;
    }
}

// stage 1: act = silu(x@gateT)*(x@upT); all staging via global_load_lds,
// LDS in fragment order -> conflict-free ds_read_b128 at base+lane*16
__global__ __launch_bounds__(256) void stage1_kernel(char* __restrict__ ws)
{
    uint32_t* meta = (uint32_t*)(ws + WS_META);
    int mtile = blockIdx.y;
    int ntile = imin((int)meta[M_NTILE], MAX_TILES);
    if (mtile >= ntile) return;
    int e = imin((int)meta[M_TE + mtile], NE);
    int slot0 = imin((int)meta[M_TB + mtile], NSLOT - 64);
    if (slot0 < 0) slot0 = 0;
    const bf16* BgF = (e < NE) ? (const bf16*)(ws + WS_GATET) + (size_t)e * HID * IDIM
                               : (const bf16*)(ws + WS_SGT);
    const bf16* BuF = (e < NE) ? (const bf16*)(ws + WS_UPT) + (size_t)e * HID * IDIM
                               : (const bf16*)(ws + WS_SUT);
    const uint32_t* perm = (const uint32_t*)(ws + WS_PERM);
    const bf16* xbf = (const bf16*)(ws + WS_DOUT);
    bf16* act = (bf16*)(ws + WS_ACT);

    __shared__ bf16 As[4096];        // [m4][kk][lane][8]
    __shared__ bf16 Bgs[8192];       // [wv][nt][kk][lane][8]
    __shared__ bf16 Bus[8192];

    int tid = threadIdx.x, lane = tid & 63, wv = tid >> 6;
    int q = lane >> 4, m = lane & 15;

    // A gather source: wave wv stages rows m4==wv
    int tok = (int)(perm[slot0 + wv * 16 + m] & (NTOK - 1));
    const bf16* gA = xbf + (size_t)tok * HID + q * 8;
    int N32 = blockIdx.x * 4 + wv;
    const bf16* gBg = BgF + (size_t)N32 * 32768 + lane * 8;
    const bf16* gBu = BuF + (size_t)N32 * 32768 + lane * 8;

    f32x4 zero4 = {0.f, 0.f, 0.f, 0.f};
    f32x4 accg[4][2], accu[4][2];
#pragma unroll
    for (int a = 0; a < 4; a++)
#pragma unroll
        for (int b = 0; b < 2; b++) { accg[a][b] = zero4; accu[a][b] = zero4; }

    for (int k0 = 0; k0 < HID; k0 += 64) {
        int kc = k0 >> 5;
        gload16(gA + k0,      &As[(wv * 2 + 0) * 512]);
        gload16(gA + k0 + 32, &As[(wv * 2 + 1) * 512]);
#pragma unroll
        for (int nt = 0; nt < 2; nt++)
#pragma unroll
            for (int kk = 0; kk < 2; kk++) {
                size_t so = (size_t)(kc + kk) * 1024 + nt * 512;
                gload16(gBg + so, &Bgs[((wv * 2 + nt) * 2 + kk) * 512]);
                gload16(gBu + so, &Bus[((wv * 2 + nt) * 2 + kk) * 512]);
            }
        __syncthreads();
#pragma unroll
        for (int kk = 0; kk < 2; kk++) {
            bf16x8 af[4];
#pragma unroll
            for (int m4 = 0; m4 < 4; m4++)
                af[m4] = *(bf16x8*)&As[((m4 * 2 + kk) * 64 + lane) * 8];
#pragma unroll
            for (int nt = 0; nt < 2; nt++) {
                bf16x8 bg = *(bf16x8*)&Bgs[(((wv * 2 + nt) * 2 + kk) * 64 + lane) * 8];
                bf16x8 bu = *(bf16x8*)&Bus[(((wv * 2 + nt) * 2 + kk) * 64 + lane) * 8];
#pragma unroll
                for (int m4 = 0; m4 < 4; m4++) {
                    accg[m4][nt] = __builtin_amdgcn_mfma_f32_16x16x32_bf16(af[m4], bg, accg[m4][nt], 0, 0, 0);
                    accu[m4][nt] = __builtin_amdgcn_mfma_f32_16x16x32_bf16(af[m4], bu, accu[m4][nt], 0, 0, 0);
                }
            }
        }
        __syncthreads();
    }
    // epilogue: write act in stage2-A fragment order
    size_t tb = (size_t)(slot0 >> 6) * 64;
#pragma unroll
    for (int m4 = 0; m4 < 4; m4++)
#pragma unroll
        for (int nt = 0; nt < 2; nt++) {
            int col = blockIdx.x * 128 + wv * 32 + nt * 16 + m;
            size_t base = ((tb + (col >> 5)) * 4 + m4) * 512
                        + (size_t)((((col >> 3) & 3) * 16) * 8) + (col & 7);
#pragma unroll
            for (int r = 0; r < 4; r++) {
                float g = accg[m4][nt][r], u = accu[m4][nt][r];
                float v = g / (1.f + __expf(-g)) * u;
                act[base + (size_t)(q * 4 + r) * 8] = (bf16)v;
            }
        }
}

// stage 2: dout = act @ downT; act already fragment-ordered
__global__ __launch_bounds__(256) void stage2_kernel(char* __restrict__ ws)
{
    uint32_t* meta = (uint32_t*)(ws + WS_META);
    int mtile = blockIdx.y;
    int ntile = imin((int)meta[M_NTILE], MAX_TILES);
    if (mtile >= ntile) return;
    int e = imin((int)meta[M_TE + mtile], NE);
    int slot0 = imin((int)meta[M_TB + mtile], NSLOT - 64);
    if (slot0 < 0) slot0 = 0;
    int n0 = blockIdx.x * 128;
    const bf16* BF = (e < NE) ? (const bf16*)(ws + WS_DOWNT) + (size_t)e * HID * IDIM
                              : (const bf16*)(ws + WS_SDT);
    const bf16* actF = (const bf16*)(ws + WS_ACT);
    bf16* dout = (bf16*)(ws + WS_DOUT);

    __shared__ bf16 As[4096];
    __shared__ bf16 Bs[8192];

    int tid = threadIdx.x, lane = tid & 63, wv = tid >> 6;
    int q = lane >> 4, m = lane & 15;

    int tile = slot0 >> 6;
    const bf16* gA = actF + ((size_t)tile * 64 * 4 + wv) * 512 + lane * 8;
    int N32 = blockIdx.x * 4 + wv;
    const bf16* gB = BF + (size_t)N32 * 65536 + lane * 8;   // [N32][64 cells]*1024

    f32x4 zero4 = {0.f, 0.f, 0.f, 0.f};
    f32x4 acc[4][2];
#pragma unroll
    for (int a = 0; a < 4; a++)
#pragma unroll
        for (int b = 0; b < 2; b++) acc[a][b] = zero4;

    for (int k0 = 0; k0 < IDIM; k0 += 64) {
        int kc = k0 >> 5;
#pragma unroll
        for (int kk = 0; kk < 2; kk++)
            gload16(gA + (size_t)(kc + kk) * 2048, &As[(wv * 2 + kk) * 512]);
#pragma unroll
        for (int nt = 0; nt < 2; nt++)
#pragma unroll
            for (int kk = 0; kk < 2; kk++)
                gload16(gB + (size_t)(kc + kk) * 1024 + nt * 512,
                        &Bs[((wv * 2 + nt) * 2 + kk) * 512]);
        __syncthreads();
#pragma unroll
        for (int kk = 0; kk < 2; kk++) {
            bf16x8 af[4];
#pragma unroll
            for (int m4 = 0; m4 < 4; m4++)
                af[m4] = *(bf16x8*)&As[((m4 * 2 + kk) * 64 + lane) * 8];
#pragma unroll
            for (int nt = 0; nt < 2; nt++) {
                bf16x8 bfr = *(bf16x8*)&Bs[(((wv * 2 + nt) * 2 + kk) * 64 + lane) * 8];
#pragma unroll
                for (int m4 = 0; m4 < 4; m4++)
                    acc[m4][nt] = __builtin_amdgcn_mfma_f32_16x16x32_bf16(af[m4], bfr, acc[m4][nt], 0, 0, 0);
            }
        }
        __syncthreads();
    }
#pragma unroll
    for (int m4 = 0; m4 < 4; m4++)
#pragma unroll
        for (int nt = 0; nt < 2; nt++)
#pragma unroll
            for (int r = 0; r < 4; r++) {
                int slot = slot0 + m4 * 16 + q * 4 + r;
                int col = n0 + wv * 32 + nt * 16 + m;
                dout[(size_t)slot * HID + col] = (bf16)acc[m4][nt][r];
            }
}

__global__ __launch_bounds__(256) void combine_kernel(char* __restrict__ ws, float* __restrict__ out)
{
    int g = blockIdx.x * 256 + threadIdx.x;
    int t = g >> 7;
    int hc = (g & 127) * 8;
    const uint32_t* slot_of = (const uint32_t*)(ws + WS_SLOTOF);
    const float* tok_w = (const float*)(ws + WS_TOKW);
    const bf16* dout = (const bf16*)(ws + WS_DOUT);
    uint32_t s0 = slot_of[2 * t], s1 = slot_of[2 * t + 1];
    if (s0 >= NSLOT) s0 = 0;
    if (s1 >= NSLOT) s1 = 0;
    float w0 = tok_w[2 * t], w1 = tok_w[2 * t + 1];
    bf16x8 a = *(const bf16x8*)&dout[(size_t)s0 * HID + hc];
    bf16x8 b = *(const bf16x8*)&dout[(size_t)s1 * HID + hc];
    bf16x8 c = *(const bf16x8*)&dout[(size_t)(SH_BASE + t) * HID + hc];
    f32x4 o0, o1;
#pragma unroll
    for (int j = 0; j < 4; j++)
        o0[j] = w0 * (float)a[j] + w1 * (float)b[j] + (float)c[j];
#pragma unroll
    for (int j = 0; j < 4; j++)
        o1[j] = w0 * (float)a[j + 4] + w1 * (float)b[j + 4] + (float)c[j + 4];
    *(f32x4*)&out[(size_t)t * HID + hc] = o0;
    *(f32x4*)&out[(size_t)t * HID + hc + 4] = o1;
}

extern "C" void kernel_launch(void* const* d_in, const int* in_sizes, int n_in,
                              void* d_out, int out_size, void* d_ws, size_t ws_size,
                              hipStream_t stream) {
    const float* x  = (const float*)d_in[0];
    const float* rw = (const float*)d_in[1];
    const float* gw = (const float*)d_in[2];
    const float* uw = (const float*)d_in[3];
    const float* dw = (const float*)d_in[4];
    const float* sg = (const float*)d_in[5];
    const float* su = (const float*)d_in[6];
    const float* sd = (const float*)d_in[7];
    float* out = (float*)d_out;
    char* ws = (char*)d_ws;
    uint32_t* meta = (uint32_t*)(ws + WS_META);
    uint32_t* perm = (uint32_t*)(ws + WS_PERM);
    int* tok_e = (int*)(ws + WS_TOKE);
    float* tok_w = (float*)(ws + WS_TOKW);
    uint32_t* slot_of = (uint32_t*)(ws + WS_SLOTOF);
    bf16* xbf = (bf16*)(ws + WS_DOUT);   // aliased: consumed by stage1, then dout overwrites

    hipLaunchKernelGGL(zero_kernel, dim3(1), dim3(64), 0, stream, meta);
    hipLaunchKernelGGL(router_kernel, dim3(NTOK / 16), dim3(1024), 0, stream,
                       x, rw, out, meta, tok_e, tok_w, xbf);
    hipLaunchKernelGGL(offsets_kernel, dim3(1), dim3(64), 0, stream, meta, out);
    hipLaunchKernelGGL(fill_kernel, dim3((NSLOT + 255) / 256), dim3(256), 0, stream, perm);
    hipLaunchKernelGGL(dispatch_kernel, dim3(NTOK / 256), dim3(256), 0, stream,
                       meta, tok_e, perm, slot_of);
    hipLaunchKernelGGL(transpose_kernel, dim3(27 * 512), dim3(256), 0, stream,
                       gw, uw, dw, sg, su, sd, ws);
    hipLaunchKernelGGL(stage1_kernel, dim3(IDIM / 128, MAX_TILES), dim3(256), 0, stream, ws);
    hipLaunchKernelGGL(stage2_kernel, dim3(HID / 128, MAX_TILES), dim3(256), 0, stream, ws);
    hipLaunchKernelGGL(combine_kernel, dim3(NTOK * HID / 8 / 256), dim3(256), 0, stream, ws, out);
}

// Round 7
// 509.122 us; speedup vs baseline: 1.2934x; 1.0811x over previous
//
#include <hip/hip_runtime.h>
#include <hip/hip_bf16.h>
#include <stdint.h>
#include <stddef.h>

typedef __bf16 bf16;
typedef __bf16 bf16x8 __attribute__((ext_vector_type(8)));
typedef __bf16 bf16x4 __attribute__((ext_vector_type(4)));
typedef float f32x4 __attribute__((ext_vector_type(4)));

#define HID 1024
#define IDIM 2048
#define NE 8
#define NTOK 4096
#define NSLOT 13312          // 9216 routed-padded (128-aligned per expert) + 4096 shared
#define SH_BASE 9216
#define MAX_TILES 104        // <=72 routed + 32 shared, all 128-slot tiles

// ---- workspace byte offsets ----
#define WS_META    0
#define WS_PERM    4096                    // u32[13312]
#define WS_TOKE    57344                   // i32[8192]
#define WS_TOKW    90112                   // f32[8192]
#define WS_SLOTOF  122880                  // u32[8192]
#define WS_XBF     155648                  // bf16[4096][1024]
#define WS_GATET   8544256                 // 33.5MB; after stage1, ALIASED as dout
#define WS_UPT     42098688
#define WS_DOWNT   75653120
#define WS_SGT     109207552
#define WS_SUT     113401856
#define WS_SDT     117596160
#define WS_ACT     121790464               // 104 tiles x 262144 elems, frag order -> ends 176.3MB
#define WS_DOUT    WS_GATET                // alias (stage2 writes after gate weights dead)

// meta u32-index layout
#define M_CNT 0
#define M_CUR 8
#define M_PSUM 16
#define M_ZSUM 24
#define M_AOFF 32
#define M_NTILE 48
#define M_TE 64
#define M_TB 320

#define OUT_AUX 4194304
#define OUT_Z   4194305
#define OUT_LG  4194306

__device__ __forceinline__ int imin(int a, int b) { return a < b ? a : b; }

typedef const __attribute__((address_space(1))) uint32_t* as1_u32p;
typedef __attribute__((address_space(3))) uint32_t* as3_u32p;

__device__ __forceinline__ void gload16(const void* g, void* l) {
    __builtin_amdgcn_global_load_lds((as1_u32p)g, (as3_u32p)l, 16, 0, 0);
}

__global__ void zero_kernel(uint32_t* meta) {
    if (threadIdx.x < 32) meta[threadIdx.x] = 0;
}

// 16 tokens/block; LDS-aggregated atomics; emits x as bf16
__global__ __launch_bounds__(1024) void router_kernel(
    const float* __restrict__ x, const float* __restrict__ rw,
    float* __restrict__ out, uint32_t* meta, int* tok_e, float* tok_w,
    bf16* __restrict__ xbf)
{
    __shared__ float s_psum[NE];
    __shared__ float s_zsum;
    __shared__ uint32_t s_cnt[NE];
    int tid = threadIdx.x;
    if (tid < NE) { s_psum[tid] = 0.f; s_cnt[tid] = 0u; }
    if (tid == NE) s_zsum = 0.f;
    __syncthreads();

    int lane = tid & 63, wv = tid >> 6;
    int t = blockIdx.x * 16 + wv;
    float acc[NE];
#pragma unroll
    for (int e = 0; e < NE; e++) acc[e] = 0.f;
#pragma unroll
    for (int it = 0; it < 4; it++) {
        int h0 = (lane + it * 64) * 4;
        f32x4 xv = *(const f32x4*)&x[(size_t)t * HID + h0];
        bf16x4 xb;
#pragma unroll
        for (int j = 0; j < 4; j++) xb[j] = (bf16)xv[j];
        *(bf16x4*)&xbf[(size_t)t * HID + h0] = xb;
#pragma unroll
        for (int j = 0; j < 4; j++) {
            float xf = xv[j];
            const float* wrow = rw + (size_t)(h0 + j) * NE;
            f32x4 w0 = *(const f32x4*)wrow;
            f32x4 w1 = *(const f32x4*)(wrow + 4);
#pragma unroll
            for (int e = 0; e < 4; e++) { acc[e] += xf * w0[e]; acc[e + 4] += xf * w1[e]; }
        }
    }
#pragma unroll
    for (int off = 32; off >= 1; off >>= 1)
#pragma unroll
        for (int e = 0; e < NE; e++) acc[e] += __shfl_xor(acc[e], off);

    if (lane == 0) {
        float mx = acc[0];
        for (int e = 1; e < NE; e++) mx = fmaxf(mx, acc[e]);
        float p[NE], s = 0.f;
        for (int e = 0; e < NE; e++) { p[e] = __expf(acc[e] - mx); s += p[e]; }
        float lse = mx + __logf(s);
        atomicAdd(&s_zsum, lse * lse);
        float inv = 1.f / s;
        for (int e = 0; e < NE; e++) {
            p[e] *= inv;
            atomicAdd(&s_psum[e], p[e]);
            out[(size_t)OUT_LG + (size_t)t * NE + e] = acc[e];
        }
        int e0 = 0;
        for (int e = 1; e < NE; e++) if (p[e] > p[e0]) e0 = e;
        int e1 = (e0 == 0) ? 1 : 0;
        for (int e = 0; e < NE; e++) if (e != e0 && p[e] > p[e1]) e1 = e;
        float wn = 1.f / (p[e0] + p[e1]);
        tok_e[2 * t] = e0; tok_e[2 * t + 1] = e1;
        tok_w[2 * t] = p[e0] * wn; tok_w[2 * t + 1] = p[e1] * wn;
        atomicAdd(&s_cnt[e0], 1u);
        atomicAdd(&s_cnt[e1], 1u);
    }
    __syncthreads();
    if (tid < NE) {
        atomicAdd((float*)&meta[M_PSUM + tid], s_psum[tid]);
        atomicAdd(&meta[M_CNT + tid], s_cnt[tid]);
    }
    if (tid == NE) atomicAdd((float*)&meta[M_ZSUM], s_zsum);
}

// one wave; 128-aligned per-expert offsets; tile table at 128 granularity
__global__ void offsets_kernel(uint32_t* meta, float* out) {
    __shared__ uint32_t s_aoff[NE + 1];
    int lane = threadIdx.x;
    if (lane == 0) {
        uint32_t off = 0;
        for (int e = 0; e < NE; e++) {
            meta[M_AOFF + e] = off; s_aoff[e] = off;
            off += ((meta[M_CNT + e] + 127) >> 7) << 7;
        }
        meta[M_AOFF + NE] = off; s_aoff[NE] = off;
        float aux = 0.f;
        for (int e = 0; e < NE; e++) {
            float tpe = (float)meta[M_CNT + e] / (2.f * NTOK);
            float ppe = ((float*)meta)[M_PSUM + e] / (float)NTOK;
            aux += tpe * ppe;
        }
        out[OUT_AUX] = aux * NE;
        out[OUT_Z] = ((float*)meta)[M_ZSUM] / (float)NTOK;
    }
    __syncthreads();
    uint32_t nrt = s_aoff[NE] >> 7;
    uint32_t ntile = nrt + NTOK / 128;
    if (lane == 0) meta[M_NTILE] = ntile;
    for (uint32_t idx = lane; idx < ntile && idx < MAX_TILES; idx += 64) {
        if (idx < nrt) {
            uint32_t base = idx << 7, e = 0;
            for (int j = 1; j < NE; j++) if (base >= s_aoff[j]) e = j;
            meta[M_TE + idx] = e;
            meta[M_TB + idx] = base;
        } else {
            meta[M_TE + idx] = NE;
            meta[M_TB + idx] = SH_BASE + ((idx - nrt) << 7);
        }
    }
}

__global__ void fill_kernel(uint32_t* perm) {
    int g = blockIdx.x * 256 + threadIdx.x;
    if (g < NSLOT) perm[g] = (g < SH_BASE) ? 0u : (uint32_t)(g - SH_BASE);
}

__global__ void dispatch_kernel(uint32_t* meta, const int* tok_e,
                                uint32_t* perm, uint32_t* slot_of) {
    int t = blockIdx.x * 256 + threadIdx.x;
    int lane = threadIdx.x & 63;
    for (int k = 0; k < 2; k++) {
        int e = tok_e[2 * t + k] & 7;
#pragma unroll
        for (int ee = 0; ee < NE; ee++) {
            bool mine = (e == ee);
            unsigned long long mask = __ballot(mine);
            if (mask == 0ull) continue;
            int leader = __ffsll((unsigned long long)mask) - 1;
            uint32_t wbase = 0;
            if (lane == leader)
                wbase = atomicAdd(&meta[M_CUR + ee], (uint32_t)__popcll(mask));
            wbase = __shfl(wbase, leader);
            if (mine) {
                uint32_t myrank = (uint32_t)__popcll(mask & ((1ull << lane) - 1ull));
                uint32_t slot = meta[M_AOFF + ee] + wbase + myrank;
                if (slot >= NSLOT) slot = 0;
                perm[slot] = (uint32_t)t;
                slot_of[2 * t + k] = slot;
            }
        }
    }
}

// fragment-order offset for W^T[n][k]: frag = ((ncell*KB32 + kcell)*2 + nt)*512
__device__ __forceinline__ size_t f_off(int n, int k, int KB32) {
    return ((size_t)((n >> 5) * KB32 + (k >> 5)) * 2 + ((n >> 4) & 1)) * 512
         + (size_t)((((k >> 3) & 3) * 16 + (n & 15)) * 8);
}

__global__ __launch_bounds__(256) void transpose_kernel(
    const float* gw, const float* uw, const float* dw,
    const float* sg, const float* su, const float* sd, char* ws)
{
    int mat = blockIdx.x >> 9, tile = blockIdx.x & 511;
    const float* src; bf16* dst; int R, C;
    const size_t MSZ = (size_t)HID * IDIM;
    if (mat < 8)       { src = gw + mat * MSZ;        dst = (bf16*)(ws + WS_GATET) + mat * MSZ; R = HID;  C = IDIM; }
    else if (mat < 16) { src = uw + (mat - 8) * MSZ;  dst = (bf16*)(ws + WS_UPT) + (mat - 8) * MSZ; R = HID; C = IDIM; }
    else if (mat < 24) { src = dw + (mat - 16) * MSZ; dst = (bf16*)(ws + WS_DOWNT) + (mat - 16) * MSZ; R = IDIM; C = HID; }
    else if (mat == 24){ src = sg; dst = (bf16*)(ws + WS_SGT); R = HID; C = IDIM; }
    else if (mat == 25){ src = su; dst = (bf16*)(ws + WS_SUT); R = HID; C = IDIM; }
    else               { src = sd; dst = (bf16*)(ws + WS_SDT); R = IDIM; C = HID; }
    int KB32 = R >> 5;
    int tpr = C >> 6;
    int r0 = (tile / tpr) * 64, c0 = (tile % tpr) * 64;   // r0 = k, c0 = n
    __shared__ bf16 tl[64][65];
    int tid = threadIdx.x;
#pragma unroll
    for (int it = 0; it < 4; it++) {
        int idx = tid + it * 256;
        int r = idx >> 4, c4 = (idx & 15) * 4;
        f32x4 v = *(const f32x4*)&src[(size_t)(r0 + r) * C + c0 + c4];
#pragma unroll
        for (int j = 0; j < 4; j++) tl[c4 + j][r] = (bf16)v[j];
    }
    __syncthreads();
#pragma unroll
    for (int it = 0; it < 2; it++) {
        int idx = tid + it * 256;
        int rr = idx >> 3, c8 = (idx & 7) * 8;
        int n = c0 + rr, k = r0 + c8;
        bf16x8 o;
#pragma unroll
        for (int j = 0; j < 8; j++) o[j] = tl[rr][c8 + j];
        *(bf16x8*)&dst[f_off(n, k, KB32)] = o;
    }
}

// stage 1: M=128 tile, N=128 (gate+up), 4 waves; wave = full M x 32 cols each
__global__ __launch_bounds__(256, 2) void stage1_kernel(char* __restrict__ ws)
{
    uint32_t* meta = (uint32_t*)(ws + WS_META);
    int mtile = blockIdx.y;
    int ntile = imin((int)meta[M_NTILE], MAX_TILES);
    if (mtile >= ntile) return;
    int e = imin((int)meta[M_TE + mtile], NE);
    int slot0 = imin((int)meta[M_TB + mtile], NSLOT - 128);
    if (slot0 < 0) slot0 = 0;
    const bf16* BgF = (e < NE) ? (const bf16*)(ws + WS_GATET) + (size_t)e * HID * IDIM
                               : (const bf16*)(ws + WS_SGT);
    const bf16* BuF = (e < NE) ? (const bf16*)(ws + WS_UPT) + (size_t)e * HID * IDIM
                               : (const bf16*)(ws + WS_SUT);
    const uint32_t* perm = (const uint32_t*)(ws + WS_PERM);
    const bf16* xbf = (const bf16*)(ws + WS_XBF);
    bf16* act = (bf16*)(ws + WS_ACT);

    __shared__ bf16 As[8192];       // [mc 8][kk 2][lane][8]
    __shared__ bf16 Bgs[8192];      // [wv][nt][kk][lane][8]
    __shared__ bf16 Bus[8192];

    int tid = threadIdx.x, lane = tid & 63, wv = tid >> 6;
    int q = lane >> 4, m = lane & 15;

    int tok0 = (int)(perm[slot0 + wv * 16 + m] & (NTOK - 1));
    int tok1 = (int)(perm[slot0 + (wv + 4) * 16 + m] & (NTOK - 1));
    const bf16* gA0 = xbf + (size_t)tok0 * HID + q * 8;
    const bf16* gA1 = xbf + (size_t)tok1 * HID + q * 8;
    int N32 = blockIdx.x * 4 + wv;
    const bf16* gBg = BgF + (size_t)N32 * 32768 + lane * 8;
    const bf16* gBu = BuF + (size_t)N32 * 32768 + lane * 8;

    f32x4 zero4 = {0.f, 0.f, 0.f, 0.f};
    f32x4 accg[8][2], accu[8][2];
#pragma unroll
    for (int a = 0; a < 8; a++)
#pragma unroll
        for (int b = 0; b < 2; b++) { accg[a][b] = zero4; accu[a][b] = zero4; }

    for (int k0 = 0; k0 < HID; k0 += 64) {
        int kc = k0 >> 5;
        gload16(gA0 + k0,      &As[(wv * 2 + 0) * 512]);
        gload16(gA0 + k0 + 32, &As[(wv * 2 + 1) * 512]);
        gload16(gA1 + k0,      &As[((wv + 4) * 2 + 0) * 512]);
        gload16(gA1 + k0 + 32, &As[((wv + 4) * 2 + 1) * 512]);
#pragma unroll
        for (int nt = 0; nt < 2; nt++)
#pragma unroll
            for (int kk = 0; kk < 2; kk++) {
                size_t so = (size_t)(kc + kk) * 1024 + nt * 512;
                gload16(gBg + so, &Bgs[((wv * 2 + nt) * 2 + kk) * 512]);
                gload16(gBu + so, &Bus[((wv * 2 + nt) * 2 + kk) * 512]);
            }
        __syncthreads();
#pragma unroll
        for (int kk = 0; kk < 2; kk++) {
            bf16x8 af[8];
#pragma unroll
            for (int mc = 0; mc < 8; mc++)
                af[mc] = *(bf16x8*)&As[((mc * 2 + kk) * 64 + lane) * 8];
#pragma unroll
            for (int nt = 0; nt < 2; nt++) {
                bf16x8 bg = *(bf16x8*)&Bgs[(((wv * 2 + nt) * 2 + kk) * 64 + lane) * 8];
                bf16x8 bu = *(bf16x8*)&Bus[(((wv * 2 + nt) * 2 + kk) * 64 + lane) * 8];
#pragma unroll
                for (int mc = 0; mc < 8; mc++) {
                    accg[mc][nt] = __builtin_amdgcn_mfma_f32_16x16x32_bf16(af[mc], bg, accg[mc][nt], 0, 0, 0);
                    accu[mc][nt] = __builtin_amdgcn_mfma_f32_16x16x32_bf16(af[mc], bu, accu[mc][nt], 0, 0, 0);
                }
            }
        }
        __syncthreads();
    }
    // epilogue: act in stage2-A fragment order: [tile][kcell 64][mc 8][512]
    int tile = slot0 >> 7;
    int kcell = blockIdx.x * 4 + wv;
    size_t tbase = (size_t)tile * 262144;
#pragma unroll
    for (int mc = 0; mc < 8; mc++)
#pragma unroll
        for (int nt = 0; nt < 2; nt++) {
            int kc2 = nt * 2 + (m >> 3);
            size_t base = tbase + (size_t)(kcell * 8 + mc) * 512
                        + (size_t)(kc2 * 16) * 8 + (m & 7);
#pragma unroll
            for (int r = 0; r < 4; r++) {
                float g = accg[mc][nt][r], u = accu[mc][nt][r];
                float v = g / (1.f + __expf(-g)) * u;
                act[base + (size_t)(q * 4 + r) * 8] = (bf16)v;
            }
        }
}

// stage 2: dout = act @ downT; M=128 tile, N=128, act fragment-ordered
__global__ __launch_bounds__(256, 3) void stage2_kernel(char* __restrict__ ws)
{
    uint32_t* meta = (uint32_t*)(ws + WS_META);
    int mtile = blockIdx.y;
    int ntile = imin((int)meta[M_NTILE], MAX_TILES);
    if (mtile >= ntile) return;
    int e = imin((int)meta[M_TE + mtile], NE);
    int slot0 = imin((int)meta[M_TB + mtile], NSLOT - 128);
    if (slot0 < 0) slot0 = 0;
    int n0 = blockIdx.x * 128;
    const bf16* BF = (e < NE) ? (const bf16*)(ws + WS_DOWNT) + (size_t)e * HID * IDIM
                              : (const bf16*)(ws + WS_SDT);
    const bf16* actF = (const bf16*)(ws + WS_ACT);
    bf16* dout = (bf16*)(ws + WS_DOUT);

    __shared__ bf16 As[8192];
    __shared__ bf16 Bs[8192];

    int tid = threadIdx.x, lane = tid & 63, wv = tid >> 6;
    int q = lane >> 4, m = lane & 15;

    int tile = slot0 >> 7;
    size_t tbase = (size_t)tile * 262144;
    const bf16* gA = actF + tbase + lane * 8;
    int N32 = blockIdx.x * 4 + wv;
    const bf16* gB = BF + (size_t)N32 * 65536 + lane * 8;

    f32x4 zero4 = {0.f, 0.f, 0.f, 0.f};
    f32x4 acc[8][2];
#pragma unroll
    for (int a = 0; a < 8; a++)
#pragma unroll
        for (int b = 0; b < 2; b++) acc[a][b] = zero4;

    for (int k0 = 0; k0 < IDIM; k0 += 64) {
        int kc = k0 >> 5;
#pragma unroll
        for (int kk = 0; kk < 2; kk++) {
            gload16(gA + (size_t)((kc + kk) * 8 + wv) * 512,     &As[(wv * 2 + kk) * 512]);
            gload16(gA + (size_t)((kc + kk) * 8 + wv + 4) * 512, &As[((wv + 4) * 2 + kk) * 512]);
        }
#pragma unroll
        for (int nt = 0; nt < 2; nt++)
#pragma unroll
            for (int kk = 0; kk < 2; kk++)
                gload16(gB + (size_t)(kc + kk) * 1024 + nt * 512,
                        &Bs[((wv * 2 + nt) * 2 + kk) * 512]);
        __syncthreads();
#pragma unroll
        for (int kk = 0; kk < 2; kk++) {
            bf16x8 af[8];
#pragma unroll
            for (int mc = 0; mc < 8; mc++)
                af[mc] = *(bf16x8*)&As[((mc * 2 + kk) * 64 + lane) * 8];
#pragma unroll
            for (int nt = 0; nt < 2; nt++) {
                bf16x8 bfr = *(bf16x8*)&Bs[(((wv * 2 + nt) * 2 + kk) * 64 + lane) * 8];
#pragma unroll
                for (int mc = 0; mc < 8; mc++)
                    acc[mc][nt] = __builtin_amdgcn_mfma_f32_16x16x32_bf16(af[mc], bfr, acc[mc][nt], 0, 0, 0);
            }
        }
        __syncthreads();
    }
#pragma unroll
    for (int mc = 0; mc < 8; mc++)
#pragma unroll
        for (int nt = 0; nt < 2; nt++)
#pragma unroll
            for (int r = 0; r < 4; r++) {
                int slot = slot0 + mc * 16 + q * 4 + r;
                int col = n0 + wv * 32 + nt * 16 + m;
                dout[(size_t)slot * HID + col] = (bf16)acc[mc][nt][r];
            }
}

__global__ __launch_bounds__(256) void combine_kernel(char* __restrict__ ws, float* __restrict__ out)
{
    int g = blockIdx.x * 256 + threadIdx.x;
    int t = g >> 7;
    int hc = (g & 127) * 8;
    const uint32_t* slot_of = (const uint32_t*)(ws + WS_SLOTOF);
    const float* tok_w = (const float*)(ws + WS_TOKW);
    const bf16* dout = (const bf16*)(ws + WS_DOUT);
    uint32_t s0 = slot_of[2 * t], s1 = slot_of[2 * t + 1];
    if (s0 >= NSLOT) s0 = 0;
    if (s1 >= NSLOT) s1 = 0;
    float w0 = tok_w[2 * t], w1 = tok_w[2 * t + 1];
    bf16x8 a = *(const bf16x8*)&dout[(size_t)s0 * HID + hc];
    bf16x8 b = *(const bf16x8*)&dout[(size_t)s1 * HID + hc];
    bf16x8 c = *(const bf16x8*)&dout[(size_t)(SH_BASE + t) * HID + hc];
    f32x4 o0, o1;
#pragma unroll
    for (int j = 0; j < 4; j++)
        o0[j] = w0 * (float)a[j] + w1 * (float)b[j] + (float)c[j];
#pragma unroll
    for (int j = 0; j < 4; j++)
        o1[j] = w0 * (float)a[j + 4] + w1 * (float)b[j + 4] + (float)c[j + 4];
    *(f32x4*)&out[(size_t)t * HID + hc] = o0;
    *(f32x4*)&out[(size_t)t * HID + hc + 4] = o1;
}

extern "C" void kernel_launch(void* const* d_in, const int* in_sizes, int n_in,
                              void* d_out, int out_size, void* d_ws, size_t ws_size,
                              hipStream_t stream) {
    const float* x  = (const float*)d_in[0];
    const float* rw = (const float*)d_in[1];
    const float* gw = (const float*)d_in[2];
    const float* uw = (const float*)d_in[3];
    const float* dw = (const float*)d_in[4];
    const float* sg = (const float*)d_in[5];
    const float* su = (const float*)d_in[6];
    const float* sd = (const float*)d_in[7];
    float* out = (float*)d_out;
    char* ws = (char*)d_ws;
    uint32_t* meta = (uint32_t*)(ws + WS_META);
    uint32_t* perm = (uint32_t*)(ws + WS_PERM);
    int* tok_e = (int*)(ws + WS_TOKE);
    float* tok_w = (float*)(ws + WS_TOKW);
    uint32_t* slot_of = (uint32_t*)(ws + WS_SLOTOF);
    bf16* xbf = (bf16*)(ws + WS_XBF);

    hipLaunchKernelGGL(zero_kernel, dim3(1), dim3(64), 0, stream, meta);
    hipLaunchKernelGGL(router_kernel, dim3(NTOK / 16), dim3(1024), 0, stream,
                       x, rw, out, meta, tok_e, tok_w, xbf);
    hipLaunchKernelGGL(offsets_kernel, dim3(1), dim3(64), 0, stream, meta, out);
    hipLaunchKernelGGL(fill_kernel, dim3((NSLOT + 255) / 256), dim3(256), 0, stream, perm);
    hipLaunchKernelGGL(dispatch_kernel, dim3(NTOK / 256), dim3(256), 0, stream,
                       meta, tok_e, perm, slot_of);
    hipLaunchKernelGGL(transpose_kernel, dim3(27 * 512), dim3(256), 0, stream,
                       gw, uw, dw, sg, su, sd, ws);
    hipLaunchKernelGGL(stage1_kernel, dim3(IDIM / 128, MAX_TILES), dim3(256), 0, stream, ws);
    hipLaunchKernelGGL(stage2_kernel, dim3(HID / 128, MAX_TILES), dim3(256), 0, stream, ws);
    hipLaunchKernelGGL(combine_kernel, dim3(NTOK * HID / 8 / 256), dim3(256), 0, stream, ws, out);
}